// Round 1
// baseline (658.314 us; speedup 1.0000x reference)
//
#include <hip/hip_runtime.h>

// ---------------------------------------------------------------------------
// Pass 1: gather + segment-sum.
// domain_ids are SORTED, so each segment is a contiguous run of entries.
// One wave processes a contiguous range of entries; lane l owns channel l
// (C_IN = 64 = wavefront size). Run accumulation stays in a register;
// flushes go through atomicAdd (only range-boundary domains are contested).
// Index loads are lane-batched (coalesced) and broadcast via __shfl.
// ---------------------------------------------------------------------------
__global__ void seg_sum_kernel(const float* __restrict__ feat,
                               const int* __restrict__ aidx,
                               const int* __restrict__ dids,
                               float* __restrict__ T,
                               int E, int epw) {
    int gwave = (int)(((long)blockIdx.x * blockDim.x + threadIdx.x) >> 6);
    int lane  = threadIdx.x & 63;
    long start = (long)gwave * epw;
    if (start >= E) return;
    long end = start + epw;
    if (end > E) end = E;

    int   cur = dids[start];
    float acc = 0.f;

    long base = start;
    while (base < end) {
        int n = (int)((end - base) < 64 ? (end - base) : 64);
        int my_d = 0, my_a = 0;
        if (lane < n) {
            my_d = dids[base + lane];
            my_a = aidx[base + lane];
        }
        if (n == 64) {
#pragma unroll 8
            for (int j = 0; j < 64; ++j) {
                int d = __shfl(my_d, j);
                int a = __shfl(my_a, j);
                float v = feat[(long)a * 64 + lane];
                if (d != cur) {
                    atomicAdd(&T[(long)cur * 64 + lane], acc);
                    acc = 0.f;
                    cur = d;
                }
                acc += v;
            }
        } else {
            for (int j = 0; j < n; ++j) {
                int d = __shfl(my_d, j);
                int a = __shfl(my_a, j);
                float v = feat[(long)a * 64 + lane];
                if (d != cur) {
                    atomicAdd(&T[(long)cur * 64 + lane], acc);
                    acc = 0.f;
                    cur = d;
                }
                acc += v;
            }
        }
        base += 64;
    }
    atomicAdd(&T[(long)cur * 64 + lane], acc);
}

// ---------------------------------------------------------------------------
// Pass 2: out[row] = T[row] @ W + b.   T: [M,64], W: [64,128], out: [M,128].
// One block (128 threads) per row: the T-row loads are block-uniform
// (scalarize to s_load); W reads are coalesced across threads and L1-hot
// (W is only 32 KB); output store is a coalesced 512 B per block.
// ---------------------------------------------------------------------------
__global__ void __launch_bounds__(128)
proj_kernel(const float* __restrict__ T,
            const float* __restrict__ W,
            const float* __restrict__ bias,
            float* __restrict__ out, int M) {
    int  c   = threadIdx.x;        // 0..127 output channel
    long row = blockIdx.x;
    if (row >= M) return;
    const float* t = T + row * 64;
    float acc = bias[c];
#pragma unroll
    for (int k = 0; k < 64; ++k) {
        acc = fmaf(t[k], W[k * 128 + c], acc);
    }
    out[row * 128 + c] = acc;
}

extern "C" void kernel_launch(void* const* d_in, const int* in_sizes, int n_in,
                              void* d_out, int out_size, void* d_ws, size_t ws_size,
                              hipStream_t stream) {
    const float* feat = (const float*)d_in[0];   // [N_ATOMS, 64] f32
    const int*   aidx = (const int*)d_in[1];     // [E] int
    const int*   dids = (const int*)d_in[2];     // [E] int (sorted)
    const float* W    = (const float*)d_in[4];   // [64, 128] f32
    const float* bias = (const float*)d_in[5];   // [128] f32
    float*       out  = (float*)d_out;           // [M, 128] f32

    int E = in_sizes[1];
    int M = out_size / 128;

    float* T = (float*)d_ws;                     // [M, 64] f32 = 64 MB scratch
    hipMemsetAsync(T, 0, (size_t)M * 64 * sizeof(float), stream);

    // ~8192 waves => ~full occupancy across 1024 SIMDs; epw multiple of 64.
    int target_waves = 8192;
    int epw = (E + target_waves - 1) / target_waves;
    epw = ((epw + 63) / 64) * 64;
    if (epw < 64) epw = 64;
    int waves   = (E + epw - 1) / epw;
    int threads = 256;
    int wpb     = threads / 64;
    int blocks  = (waves + wpb - 1) / wpb;

    seg_sum_kernel<<<blocks, threads, 0, stream>>>(feat, aidx, dids, T, E, epw);
    proj_kernel<<<M, 128, 0, stream>>>(T, W, bias, out, M);
}

// Round 2
// 563.628 us; speedup vs baseline: 1.1680x; 1.1680x over previous
//
#include <hip/hip_runtime.h>

// ---------------------------------------------------------------------------
// Kernel A: find segment boundaries in the SORTED domain_ids array.
// starts[d] = first entry index of domain d (-1 if empty, via 0xFF memset).
// ends[d]   = one-past-last entry index of domain d.
// Each nonempty domain gets exactly one writer for each value — no races.
// ---------------------------------------------------------------------------
__global__ void bounds_kernel(const int* __restrict__ dids,
                              int* __restrict__ starts,
                              int* __restrict__ ends, int E) {
    int e = blockIdx.x * blockDim.x + threadIdx.x;
    if (e >= E) return;
    int d = dids[e];
    if (e == 0) {
        starts[d] = 0;
    } else {
        int dp = dids[e - 1];
        if (d != dp) {
            starts[d] = e;
            ends[dp]  = e;
        }
    }
    if (e == E - 1) ends[d] = E;
}

// ---------------------------------------------------------------------------
// Kernel B: gather + segment-sum, one WAVE per domain.
// lane = channel (C_IN = 64 = wavefront). Entry indices are wave-uniform, so
// aidx reads compile to scalar s_load (batches of 8); the 8 feature-row loads
// per batch are independent coalesced 256 B transactions (high MLP).
// No shuffles, no atomics. Every T row is written (0 for empty domains),
// so T needs no memset.
// ---------------------------------------------------------------------------
__global__ void seg_sum_kernel(const float* __restrict__ feat,
                               const int* __restrict__ aidx,
                               const int* __restrict__ starts,
                               const int* __restrict__ ends,
                               float* __restrict__ T, int M) {
    int wid = (int)((blockIdx.x * (size_t)blockDim.x + threadIdx.x) >> 6);
    wid = __builtin_amdgcn_readfirstlane(wid);   // force wave-uniform (SGPR)
    if (wid >= M) return;
    int lane = threadIdx.x & 63;

    int s = starts[wid];          // scalar loads
    int e = ends[wid];

    float acc = 0.f;
    int base = s;
    if (s >= 0) {
        while (e - base >= 8) {
            int a0 = aidx[base + 0], a1 = aidx[base + 1];
            int a2 = aidx[base + 2], a3 = aidx[base + 3];
            int a4 = aidx[base + 4], a5 = aidx[base + 5];
            int a6 = aidx[base + 6], a7 = aidx[base + 7];
            float v0 = feat[(size_t)a0 * 64 + lane];
            float v1 = feat[(size_t)a1 * 64 + lane];
            float v2 = feat[(size_t)a2 * 64 + lane];
            float v3 = feat[(size_t)a3 * 64 + lane];
            float v4 = feat[(size_t)a4 * 64 + lane];
            float v5 = feat[(size_t)a5 * 64 + lane];
            float v6 = feat[(size_t)a6 * 64 + lane];
            float v7 = feat[(size_t)a7 * 64 + lane];
            acc += ((v0 + v1) + (v2 + v3)) + ((v4 + v5) + (v6 + v7));
            base += 8;
        }
        while (base < e) {
            int a = aidx[base];
            acc += feat[(size_t)a * 64 + lane];
            ++base;
        }
    }
    T[(size_t)wid * 64 + lane] = acc;
}

// ---------------------------------------------------------------------------
// Proj v2: out[r] = T[r] @ W + b, register-blocked.
// Thread c holds its whole W column (64 floats) in VGPRs, loaded ONCE, and
// processes R rows — W L1 traffic drops 32x vs v1 (the 200 us L1 bottleneck).
// T-row reads are block-uniform -> scalar s_load_dwordx16. 4 accumulators
// break the FMA dependency chain. Coalesced 512 B output stores.
// ---------------------------------------------------------------------------
#define PROJ_R 32
__global__ void __launch_bounds__(128)
proj_kernel(const float* __restrict__ T,
            const float* __restrict__ W,
            const float* __restrict__ bias,
            float* __restrict__ out, int M) {
    int c = threadIdx.x;                 // output channel 0..127
    float w[64];
#pragma unroll
    for (int k = 0; k < 64; ++k) w[k] = W[k * 128 + c];
    float bc = bias[c];

    int row0 = blockIdx.x * PROJ_R;
    int rend = row0 + PROJ_R;
    if (rend > M) rend = M;
    for (int r = row0; r < rend; ++r) {
        const float* t = T + (size_t)r * 64;   // uniform -> s_load
        float a0 = 0.f, a1 = 0.f, a2 = 0.f, a3 = 0.f;
#pragma unroll
        for (int k = 0; k < 64; k += 4) {
            a0 = fmaf(t[k + 0], w[k + 0], a0);
            a1 = fmaf(t[k + 1], w[k + 1], a1);
            a2 = fmaf(t[k + 2], w[k + 2], a2);
            a3 = fmaf(t[k + 3], w[k + 3], a3);
        }
        out[(size_t)r * 128 + c] = ((a0 + a1) + (a2 + a3)) + bc;
    }
}

extern "C" void kernel_launch(void* const* d_in, const int* in_sizes, int n_in,
                              void* d_out, int out_size, void* d_ws, size_t ws_size,
                              hipStream_t stream) {
    const float* feat = (const float*)d_in[0];   // [N_ATOMS, 64] f32
    const int*   aidx = (const int*)d_in[1];     // [E] int
    const int*   dids = (const int*)d_in[2];     // [E] int (sorted)
    const float* W    = (const float*)d_in[4];   // [64, 128] f32
    const float* bias = (const float*)d_in[5];   // [128] f32
    float*       out  = (float*)d_out;           // [M, 128] f32

    int E = in_sizes[1];
    int M = out_size / 128;

    float* T = (float*)d_ws;                     // [M, 64] f32 = 64 MB
    size_t tbytes = (size_t)M * 64 * sizeof(float);
    size_t bbytes = 2 * (size_t)M * sizeof(int);

    int* starts;
    if (ws_size >= tbytes + bbytes) {
        starts = (int*)((char*)d_ws + tbytes);
    } else {
        // Stash boundaries in the tail of d_out; proj overwrites it only
        // after seg_sum has consumed them (same-stream serialization).
        starts = (int*)((char*)d_out + (size_t)out_size * sizeof(float) - bbytes);
    }
    int* ends = starts + M;

    hipMemsetAsync(starts, 0xFF, bbytes, stream);   // starts/ends = -1

    bounds_kernel<<<(E + 255) / 256, 256, 0, stream>>>(dids, starts, ends, E);

    int waves_blocks = (M * 64 + 255) / 256;        // one wave per domain
    seg_sum_kernel<<<waves_blocks, 256, 0, stream>>>(feat, aidx, starts, ends, T, M);

    proj_kernel<<<(M + PROJ_R - 1) / PROJ_R, 128, 0, stream>>>(T, W, bias, out, M);
}

// Round 3
// 423.098 us; speedup vs baseline: 1.5559x; 1.3321x over previous
//
#include <hip/hip_runtime.h>

// ---------------------------------------------------------------------------
// Kernel A: segment boundaries in SORTED domain_ids.
// starts[d]=-1 (memset 0xFF) means empty domain.
// ---------------------------------------------------------------------------
__global__ void bounds_kernel(const int* __restrict__ dids,
                              int* __restrict__ starts,
                              int* __restrict__ ends, int E) {
    int e = blockIdx.x * blockDim.x + threadIdx.x;
    if (e >= E) return;
    int d = dids[e];
    if (e == 0) {
        starts[d] = 0;
    } else {
        int dp = dids[e - 1];
        if (d != dp) {
            starts[d] = e;
            ends[dp]  = e;
        }
    }
    if (e == E - 1) ends[d] = E;
}

// ---------------------------------------------------------------------------
// Kernel B v3: gather + segment-sum, one wave per domain, lane = channel.
// Fixed 16-wide batches: 16 independent 256 B gathers in flight per wave
// (tail indices clamped to e-1 -> duplicate loads are same-address, L1-hot),
// adds predicated on uniform j<rem. No serial tail chain, no vmcnt(0) drain
// between sub-batches. 32 waves/CU x 4 KB in flight = latency fully covered;
// if this is still slow it is L2/L3 random-gather BW, not latency.
// ---------------------------------------------------------------------------
__global__ void seg_sum_kernel(const float* __restrict__ feat,
                               const int* __restrict__ aidx,
                               const int* __restrict__ starts,
                               const int* __restrict__ ends,
                               float* __restrict__ T, int M) {
    int wid  = (int)(((size_t)blockIdx.x * blockDim.x + threadIdx.x) >> 6);
    if (wid >= M) return;
    int lane = threadIdx.x & 63;

    int s = starts[wid];
    int e = ends[wid];

    float acc = 0.f;
    if (s >= 0) {
        for (int base = s; base < e; base += 16) {
            int rem  = e - base;          // uniform, >= 1
            int last = e - 1;
            int ii[16];
#pragma unroll
            for (int j = 0; j < 16; ++j) {
                int t = base + j;
                ii[j] = aidx[t < e ? t : last];   // uniform addr -> s_load
            }
            float v[16];
#pragma unroll
            for (int j = 0; j < 16; ++j)
                v[j] = feat[(size_t)ii[j] * 64 + lane];
#pragma unroll
            for (int j = 0; j < 16; ++j)
                acc += (j < rem) ? v[j] : 0.f;
        }
    }
    T[(size_t)wid * 64 + lane] = acc;
}

// ---------------------------------------------------------------------------
// Proj v4: out = T @ W + b as an LDS-tiled register-blocked GEMM.
// Block 256 threads handles a 64-row x 128-col tile.
//   lds_w[k][c]          : 64x128 f32 = 32 KB (W's native layout, float4 copy)
//   lds_t[k][row]        : T tile TRANSPOSED, stride 68 floats (16B-aligned
//                          b128 reads, bank spread)
// Thread (tid) owns rows r0..r0+7 (r0=(tid>>5)*8) x cols c0..c0+3
// (c0=(tid&31)*4): per k-step 2+1 ds_read_b128 + 32 v_fma_f32, acc in 32
// VGPRs. FMA floor = 2.05e9 FMA / (256 CU * 128 lanes/cy) = 26 us.
// Stores: 32 contiguous lanes cover a full 512 B output row -> coalesced.
// ---------------------------------------------------------------------------
#define TM 64
__global__ void __launch_bounds__(256)
proj_kernel(const float* __restrict__ T,
            const float* __restrict__ W,
            const float* __restrict__ bias,
            float* __restrict__ out, int M) {
    __shared__ float lds_w[64][128];
    __shared__ float lds_t[64][TM + 4];   // stride 68 floats = 272 B (16B mult)

    int tid  = threadIdx.x;
    int row0 = blockIdx.x * TM;

    // Stage W: 8192 floats = 2048 float4, 8 per thread, coalesced.
#pragma unroll
    for (int i = 0; i < 8; ++i) {
        int idx = tid + i * 256;          // 0..2047
        int k   = idx >> 5;
        int ch  = idx & 31;
        float4 wv = ((const float4*)W)[idx];
        *(float4*)&lds_w[k][ch * 4] = wv;
    }
    // Stage T transposed: 64 rows x 16 float4 chunks, 4 per thread.
#pragma unroll
    for (int i = 0; i < 4; ++i) {
        int idx = tid + i * 256;          // 0..1023
        int r   = idx >> 4;
        int ch  = idx & 15;
        long gr = row0 + r;
        if (gr > (long)M - 1) gr = M - 1; // clamp: valid mem, stores guarded
        float4 tv = ((const float4*)(T + gr * 64))[ch];
        lds_t[ch * 4 + 0][r] = tv.x;
        lds_t[ch * 4 + 1][r] = tv.y;
        lds_t[ch * 4 + 2][r] = tv.z;
        lds_t[ch * 4 + 3][r] = tv.w;
    }
    __syncthreads();

    int c0 = (tid & 31) * 4;
    int r0 = (tid >> 5) * 8;

    float acc[8][4];
#pragma unroll
    for (int r = 0; r < 8; ++r)
#pragma unroll
        for (int c = 0; c < 4; ++c) acc[r][c] = 0.f;

#pragma unroll 8
    for (int k = 0; k < 64; ++k) {
        float4 ta = *(const float4*)&lds_t[k][r0];
        float4 tb = *(const float4*)&lds_t[k][r0 + 4];
        float4 wv = *(const float4*)&lds_w[k][c0];
        float t[8] = {ta.x, ta.y, ta.z, ta.w, tb.x, tb.y, tb.z, tb.w};
        float w[4] = {wv.x, wv.y, wv.z, wv.w};
#pragma unroll
        for (int r = 0; r < 8; ++r)
#pragma unroll
            for (int c = 0; c < 4; ++c)
                acc[r][c] = fmaf(t[r], w[c], acc[r][c]);
    }

    float4 bv = *(const float4*)&bias[c0];
#pragma unroll
    for (int r = 0; r < 8; ++r) {
        long row = row0 + r0 + r;
        if (row < M) {
            float4 o;
            o.x = acc[r][0] + bv.x;
            o.y = acc[r][1] + bv.y;
            o.z = acc[r][2] + bv.z;
            o.w = acc[r][3] + bv.w;
            *(float4*)&out[row * 128 + c0] = o;
        }
    }
}

extern "C" void kernel_launch(void* const* d_in, const int* in_sizes, int n_in,
                              void* d_out, int out_size, void* d_ws, size_t ws_size,
                              hipStream_t stream) {
    const float* feat = (const float*)d_in[0];   // [N_ATOMS, 64] f32
    const int*   aidx = (const int*)d_in[1];     // [E] int
    const int*   dids = (const int*)d_in[2];     // [E] int (sorted)
    const float* W    = (const float*)d_in[4];   // [64, 128] f32
    const float* bias = (const float*)d_in[5];   // [128] f32
    float*       out  = (float*)d_out;           // [M, 128] f32

    int E = in_sizes[1];
    int M = out_size / 128;

    float* T = (float*)d_ws;                     // [M, 64] f32 = 64 MB
    size_t tbytes = (size_t)M * 64 * sizeof(float);
    size_t bbytes = 2 * (size_t)M * sizeof(int);

    int* starts;
    if (ws_size >= tbytes + bbytes) {
        starts = (int*)((char*)d_ws + tbytes);
    } else {
        // Stash boundaries in the tail of d_out; proj overwrites them only
        // after seg_sum consumed them (same-stream serialization).
        starts = (int*)((char*)d_out + (size_t)out_size * sizeof(float) - bbytes);
    }
    int* ends = starts + M;

    hipMemsetAsync(starts, 0xFF, bbytes, stream);

    bounds_kernel<<<(E + 255) / 256, 256, 0, stream>>>(dids, starts, ends, E);

    int waves_blocks = (int)(((size_t)M * 64 + 255) / 256);
    seg_sum_kernel<<<waves_blocks, 256, 0, stream>>>(feat, aidx, starts, ends, T, M);

    proj_kernel<<<(M + TM - 1) / TM, 256, 0, stream>>>(T, W, bias, out, M);
}